// Round 9
// baseline (185.520 us; speedup 1.0000x reference)
//
#include <hip/hip_runtime.h>
#include <hip/hip_bf16.h>

#define B_EVENTS 4096
#define L_PTS    524288
#define CIN      16
#define C1       128
#define C2       128
#define C3       64
#define DVEC     32
#define ZDIM     96   // C3 + DVEC
#define M1       256
#define M2       128
#define BN_EPS   1e-5f
#define TILE     64
#define NTILES   (L_PTS / TILE)   // 8192

// phi LDS map (bytes)
#define XSTRIDE  72               // 64B data + 8B pad (bank spread)
#define XOFF     0                // 64 rows * 72B = 4608
#define H1OFF    4608             // 16KB swizzled
#define H2OFF    20992            // 16KB swizzled
#define LDSSZ    37376

typedef __attribute__((ext_vector_type(8))) short bf16x8;
typedef __attribute__((ext_vector_type(4))) float f32x4;

// HW packed f32->bf16 (RNE), 2 values per instruction. No builtin on gfx950.
__device__ __forceinline__ unsigned cvtpk(float lo, float hi) {
    unsigned r;
    asm("v_cvt_pk_bf16_f32 %0, %1, %2" : "=v"(r) : "v"(lo), "v"(hi));
    return r;
}

// (x + b) -> relu -> pack 4 bf16 (8B)
__device__ __forceinline__ unsigned long long pack4relub(f32x4 a, f32x4 b) {
    union { unsigned u[2]; unsigned long long ll; } pk;
    pk.u[0] = cvtpk(fmaxf(a[0] + b[0], 0.f), fmaxf(a[1] + b[1], 0.f));
    pk.u[1] = cvtpk(fmaxf(a[2] + b[2], 0.f), fmaxf(a[3] + b[3], 0.f));
    return pk.ll;
}

// build a bf16x8 A-fragment from 8 consecutive f32 weights
__device__ __forceinline__ bf16x8 frag_from_f32(const float* p) {
    const float4 lo = *(const float4*)p;
    const float4 hi = *(const float4*)(p + 4);
    union { unsigned u[4]; bf16x8 v; } r;
    r.u[0] = cvtpk(lo.x, lo.y);
    r.u[1] = cvtpk(lo.z, lo.w);
    r.u[2] = cvtpk(hi.x, hi.y);
    r.u[3] = cvtpk(hi.z, hi.w);
    return r.v;
}

// H1/H2 LDS addressing: point-major, 16B slots, XOR-swizzled by pt&7
__device__ __forceinline__ int ldsoff(int base, int rowSlots, int c, int sir) {
    int s = c * rowSlots + sir;
    s ^= (c & 7);
    return base + s * 16;
}

// ---------------------------------------------------------------------------
// Kernel 0: exclusive scan of counts -> bounds[B+1]; then per-tile map:
// tilemap[t] = event_of(t*64) | (fast<<30), fast = tile entirely in one event;
// -1 if tile start beyond total points. One block, 1024 threads.
// ---------------------------------------------------------------------------
__global__ __launch_bounds__(1024) void scan_kernel(const int* __restrict__ si,
                                                    int* __restrict__ bounds,
                                                    int* __restrict__ tilemap)
{
    __shared__ int sh[1024];
    const int tid = threadIdx.x;
    const int c0 = si[tid*4+0], c1 = si[tid*4+1], c2 = si[tid*4+2], c3 = si[tid*4+3];
    const int s4 = c0 + c1 + c2 + c3;
    sh[tid] = s4;
    __syncthreads();
    for (int off = 1; off < 1024; off <<= 1) {
        int add = (tid >= off) ? sh[tid - off] : 0;
        __syncthreads();
        sh[tid] += add;
        __syncthreads();
    }
    const int excl = (tid == 0) ? 0 : sh[tid - 1];
    bounds[tid*4+0] = excl;
    bounds[tid*4+1] = excl + c0;
    bounds[tid*4+2] = excl + c0 + c1;
    bounds[tid*4+3] = excl + c0 + c1 + c2;
    if (tid == 1023) bounds[B_EVENTS] = excl + s4;
    __syncthreads();   // bounds visible to this block (writes drained by barrier)

    const int total = bounds[B_EVENTS];
    for (int t = tid; t < NTILES; t += 1024) {
        const int p0 = t * TILE;
        if (p0 >= total) { tilemap[t] = -1; continue; }
        int e = (int)(((long long)p0 * B_EVENTS) / total);   // interpolation guess
        if (e > B_EVENTS - 1) e = B_EVENTS - 1;
        while (bounds[e] > p0) --e;
        while (bounds[e + 1] <= p0) ++e;
        const bool fast = (p0 + TILE <= bounds[e + 1]);
        tilemap[t] = e | (fast ? (1 << 30) : 0);
    }
}

// ---------------------------------------------------------------------------
// Kernel 1: flat phi — one 64-point tile per block, single shot (no loops).
// 256 threads = 4 waves, waves split M 4-way (wm=wid); each wave does full N=64.
// MFMAs/wave: L1 2x4=8, L2 2x4x4=32, L3 4x4=16.  Weights 56 VGPR, biases 20,
// acc in AGPRs -> fits __launch_bounds__(256,3) cap 170 => 3 waves/SIMD.
// LDS: X [64pt][32ch pad] 72B rows (upper 16ch zeroed; K-pad weights zero),
// H1/H2 swizzled 16KB each.  3 barriers per block, then atomics into zsum.
// Segment mean: fast path (tile inside one event, the always-case for uniform
// counts) = intra-wave shfl reduce + 64 atomics/block; slow path = per-column
// event walk + per-element atomics (correct for any counts).
// ---------------------------------------------------------------------------
__global__ __launch_bounds__(256, 3) void phi_mfma_kernel(
    const float* __restrict__ xa,
    const int* __restrict__ bounds, const int* __restrict__ tilemap,
    const float* __restrict__ W1, const float* __restrict__ W2, const float* __restrict__ W3,
    const float* __restrict__ b1, const float* __restrict__ b2, const float* __restrict__ b3,
    float* __restrict__ zsum)
{
    __shared__ __align__(16) char lds[LDSSZ];

    const int tid  = threadIdx.x;
    const int lane = tid & 63;
    const int wm   = tid >> 6;       // wave id = M quarter (0..3)
    const int g4   = lane >> 4;      // 0..3
    const int c16  = lane & 15;      // 0..15

    const int tm = tilemap[blockIdx.x];
    if (tm < 0) return;
    const int  e0    = tm & 0x3FFFFFFF;
    const bool fastp = (tm >> 30) & 1;
    const int  p0    = blockIdx.x * TILE;

    // ---- issue X loads early (coalesced 256B rows; points are contiguous
    // across events, so no per-event offset logic) ----
    const int pt = tid & 63;
    const int h  = tid >> 6;         // channel quad h*4..h*4+3
    float xv[4];
    #pragma unroll
    for (int jj = 0; jj < 4; ++jj)
        xv[jj] = xa[(size_t)(h * 4 + jj) * L_PTS + p0 + pt];

    // ---- biases in registers (loaded once, consumed in epilogues) ----
    f32x4 bb1[2], bb2[2], bb3;
    #pragma unroll
    for (int mf = 0; mf < 2; ++mf) {
        bb1[mf] = *(const f32x4*)&b1[wm * 32 + mf * 16 + g4 * 4];
        bb2[mf] = *(const f32x4*)&b2[wm * 32 + mf * 16 + g4 * 4];
    }
    bb3 = *(const f32x4*)&b3[wm * 16 + g4 * 4];

    // ---- weight A-fragments straight from f32 ----
    // lane holds A[row=lane&15][k=(lane>>4)*8+j]; W1 K-padded 16->32 via zero frags
    bf16x8 a1[2], a2[2][4], a3[4];
    {
        const bf16x8 zz = {0, 0, 0, 0, 0, 0, 0, 0};
        const int r1 = wm * 32 + c16;
        #pragma unroll
        for (int mf = 0; mf < 2; ++mf)
            a1[mf] = (g4 < 2) ? frag_from_f32(&W1[(r1 + mf * 16) * CIN + g4 * 8]) : zz;
        #pragma unroll
        for (int mf = 0; mf < 2; ++mf)
            #pragma unroll
            for (int kf = 0; kf < 4; ++kf)
                a2[mf][kf] = frag_from_f32(&W2[(r1 + mf * 16) * C1 + kf * 32 + g4 * 8]);
        const int r3 = wm * 16 + c16;
        #pragma unroll
        for (int kf = 0; kf < 4; ++kf)
            a3[kf] = frag_from_f32(&W3[r3 * C2 + kf * 32 + g4 * 8]);
    }

    // ---- write X tile + zero the K-pad upper half (bytes 32..63 of each row) ----
    {
        union { unsigned u[2]; unsigned long long ll; } pk;
        pk.u[0] = cvtpk(xv[0], xv[1]);
        pk.u[1] = cvtpk(xv[2], xv[3]);
        *(unsigned long long*)(lds + XOFF + pt * XSTRIDE + h * 8) = pk.ll;
        *(unsigned long long*)(lds + XOFF + (tid >> 2) * XSTRIDE + 32 + (tid & 3) * 8) = 0ull;
    }
    __syncthreads();                           // bar0: X ready

    // ---- layer 1: H1[128ch][64pt] = relu(W1 @ X + b1), K=32 ----
    {
        f32x4 acc[2][4];
        #pragma unroll
        for (int mf = 0; mf < 2; ++mf)
            #pragma unroll
            for (int nf = 0; nf < 4; ++nf)
                acc[mf][nf] = f32x4{0.f, 0.f, 0.f, 0.f};
        bf16x8 bfr[4];
        #pragma unroll
        for (int nf = 0; nf < 4; ++nf)
            bfr[nf] = *(const bf16x8*)(lds + XOFF + (nf * 16 + c16) * XSTRIDE + g4 * 16);
        __builtin_amdgcn_s_setprio(1);
        #pragma unroll
        for (int nf = 0; nf < 4; ++nf)
            #pragma unroll
            for (int mf = 0; mf < 2; ++mf)
                acc[mf][nf] = __builtin_amdgcn_mfma_f32_16x16x32_bf16(a1[mf], bfr[nf], acc[mf][nf], 0, 0, 0);
        __builtin_amdgcn_s_setprio(0);
        #pragma unroll
        for (int mf = 0; mf < 2; ++mf) {
            const int sir = wm * 4 + mf * 2 + (g4 >> 1);
            #pragma unroll
            for (int nf = 0; nf < 4; ++nf) {
                const int c = nf * 16 + c16;
                *(unsigned long long*)(lds + ldsoff(H1OFF, 16, c, sir) + (g4 & 1) * 8) = pack4relub(acc[mf][nf], bb1[mf]);
            }
        }
    }
    __syncthreads();                           // bar1: H1 ready

    // ---- layer 2: H2 = relu(W2 @ H1 + b2), K=128 ----
    {
        f32x4 acc[2][4];
        #pragma unroll
        for (int mf = 0; mf < 2; ++mf)
            #pragma unroll
            for (int nf = 0; nf < 4; ++nf)
                acc[mf][nf] = f32x4{0.f, 0.f, 0.f, 0.f};
        #pragma unroll
        for (int nf = 0; nf < 4; ++nf) {
            const int c = nf * 16 + c16;
            bf16x8 bk[4];
            #pragma unroll
            for (int kf = 0; kf < 4; ++kf)
                bk[kf] = *(const bf16x8*)(lds + ldsoff(H1OFF, 16, c, kf * 4 + g4));
            __builtin_amdgcn_s_setprio(1);
            #pragma unroll
            for (int mf = 0; mf < 2; ++mf)
                #pragma unroll
                for (int kf = 0; kf < 4; ++kf)
                    acc[mf][nf] = __builtin_amdgcn_mfma_f32_16x16x32_bf16(a2[mf][kf], bk[kf], acc[mf][nf], 0, 0, 0);
            __builtin_amdgcn_s_setprio(0);
        }
        #pragma unroll
        for (int mf = 0; mf < 2; ++mf) {
            const int sir = wm * 4 + mf * 2 + (g4 >> 1);
            #pragma unroll
            for (int nf = 0; nf < 4; ++nf) {
                const int c = nf * 16 + c16;
                *(unsigned long long*)(lds + ldsoff(H2OFF, 16, c, sir) + (g4 & 1) * 8) = pack4relub(acc[mf][nf], bb2[mf]);
            }
        }
    }
    __syncthreads();                           // bar2: H2 ready

    // ---- layer 3: H3 = relu(W3 @ H2 + b3); segment column-sum via atomics ----
    {
        f32x4 acc3[4];
        #pragma unroll
        for (int nf = 0; nf < 4; ++nf) acc3[nf] = f32x4{0.f, 0.f, 0.f, 0.f};
        #pragma unroll
        for (int nf = 0; nf < 4; ++nf) {
            const int c = nf * 16 + c16;
            bf16x8 bk[4];
            #pragma unroll
            for (int kf = 0; kf < 4; ++kf)
                bk[kf] = *(const bf16x8*)(lds + ldsoff(H2OFF, 16, c, kf * 4 + g4));
            __builtin_amdgcn_s_setprio(1);
            #pragma unroll
            for (int kf = 0; kf < 4; ++kf)
                acc3[nf] = __builtin_amdgcn_mfma_f32_16x16x32_bf16(a3[kf], bk[kf], acc3[nf], 0, 0, 0);
            __builtin_amdgcn_s_setprio(0);
        }

        if (fastp) {
            // whole tile in event e0, all columns valid
            float s[4] = {0.f, 0.f, 0.f, 0.f};
            #pragma unroll
            for (int nf = 0; nf < 4; ++nf)
                #pragma unroll
                for (int r = 0; r < 4; ++r)
                    s[r] += fmaxf(acc3[nf][r] + bb3[r], 0.f);
            #pragma unroll
            for (int r = 0; r < 4; ++r) {
                float v = s[r];
                v += __shfl_xor(v, 1, 64);
                v += __shfl_xor(v, 2, 64);
                v += __shfl_xor(v, 4, 64);
                v += __shfl_xor(v, 8, 64);
                s[r] = v;
            }
            if (c16 == 0) {
                #pragma unroll
                for (int r = 0; r < 4; ++r)
                    atomicAdd(&zsum[(size_t)e0 * C3 + wm * 16 + g4 * 4 + r], s[r]);
            }
        } else {
            // general path: per-column segment walk + per-element atomics
            const int total = bounds[B_EVENTS];
            #pragma unroll
            for (int nf = 0; nf < 4; ++nf) {
                const int col = p0 + nf * 16 + c16;
                if (col < total) {
                    int sgr = e0;
                    while (col >= bounds[sgr + 1]) ++sgr;
                    #pragma unroll
                    for (int r = 0; r < 4; ++r)
                        atomicAdd(&zsum[(size_t)sgr * C3 + wm * 16 + g4 * 4 + r],
                                  fmaxf(acc3[nf][r] + bb3[r], 0.f));
                }
            }
        }
    }
}

// ---------------------------------------------------------------------------
// Kernel 2: y1 = z @ Wm1.T + bm1, z = [zsum/cnt , xb]; plus column stats
// ---------------------------------------------------------------------------
__global__ __launch_bounds__(256) void mlp1_kernel(
    const float* __restrict__ zsum, const int* __restrict__ si, const float* __restrict__ xb,
    const float* __restrict__ Wm1, const float* __restrict__ bm1,
    float* __restrict__ y1, float* __restrict__ gsum, float* __restrict__ gsq)
{
    __shared__ float zs[8][ZDIM + 4];
    const int r0 = blockIdx.x * 8;
    const int tid = threadIdx.x;
    for (int i = tid; i < 8 * ZDIM; i += 256) {
        const int r = i / ZDIM, c = i - r * ZDIM;
        float v;
        if (c < C3) {
            const int cnt = si[r0 + r];
            v = zsum[(size_t)(r0 + r) * C3 + c] / (float)max(cnt, 1);
        } else {
            v = xb[(size_t)(r0 + r) * DVEC + (c - C3)];
        }
        zs[r][c] = v;
    }
    __syncthreads();
    const int o = tid;
    float acc[8];
    const float bb = bm1[o];
    #pragma unroll
    for (int r = 0; r < 8; ++r) acc[r] = bb;
    for (int c = 0; c < ZDIM; c += 4) {
        const float4 w = *(const float4*)&Wm1[o * ZDIM + c];
        #pragma unroll
        for (int r = 0; r < 8; ++r) {
            const float4 v = *(const float4*)&zs[r][c];
            acc[r] += w.x*v.x + w.y*v.y + w.z*v.z + w.w*v.w;
        }
    }
    float s = 0.f, sq = 0.f;
    #pragma unroll
    for (int r = 0; r < 8; ++r) {
        y1[(size_t)(r0 + r) * M1 + o] = acc[r];
        s += acc[r]; sq += acc[r] * acc[r];
    }
    atomicAdd(&gsum[o], s);
    atomicAdd(&gsq[o], sq);
}

// ---------------------------------------------------------------------------
// Kernel 3: y2 = relu(bn(y1)) @ Wm2.T + bm2, BN1 finalize fused; plus stats
// ---------------------------------------------------------------------------
__global__ __launch_bounds__(256) void mlp2_kernel(
    const float* __restrict__ y1,
    const float* __restrict__ gsum1, const float* __restrict__ gsq1,
    const float* __restrict__ g1, const float* __restrict__ be1,
    const float* __restrict__ Wm2, const float* __restrict__ bm2,
    float* __restrict__ y2, float* __restrict__ gsum, float* __restrict__ gsq)
{
    __shared__ float zs[8][M1 + 4];
    __shared__ float sc[M1], sh[M1];
    const int r0 = blockIdx.x * 8;
    const int tid = threadIdx.x;
    {
        const float mu  = gsum1[tid] * (1.f / B_EVENTS);
        const float var = gsq1[tid] * (1.f / B_EVENTS) - mu * mu;
        const float s0  = rsqrtf(var + BN_EPS) * g1[tid];
        sc[tid] = s0;
        sh[tid] = be1[tid] - mu * s0;
    }
    __syncthreads();
    for (int i = tid; i < 8 * M1; i += 256) {
        const int r = i >> 8, c = i & (M1 - 1);
        const float v = y1[(size_t)(r0 + r) * M1 + c];
        zs[r][c] = fmaxf(v * sc[c] + sh[c], 0.f);
    }
    __syncthreads();
    const int o = tid & 127;
    const int h = tid >> 7;
    float acc[4];
    const float bb = bm2[o];
    #pragma unroll
    for (int r = 0; r < 4; ++r) acc[r] = bb;
    for (int c = 0; c < M1; c += 4) {
        const float4 w = *(const float4*)&Wm2[o * M1 + c];
        #pragma unroll
        for (int r = 0; r < 4; ++r) {
            const float4 v = *(const float4*)&zs[h * 4 + r][c];
            acc[r] += w.x*v.x + w.y*v.y + w.z*v.z + w.w*v.w;
        }
    }
    float s = 0.f, sq = 0.f;
    #pragma unroll
    for (int r = 0; r < 4; ++r) {
        y2[(size_t)(r0 + h * 4 + r) * M2 + o] = acc[r];
        s += acc[r]; sq += acc[r] * acc[r];
    }
    atomicAdd(&gsum[o], s);
    atomicAdd(&gsq[o], sq);
}

// ---------------------------------------------------------------------------
// Kernel 4: out = sigmoid(relu(bn(y2)) @ Wm3.T + bm3), BN2 finalize fused
// ---------------------------------------------------------------------------
__global__ __launch_bounds__(256) void final_kernel(
    const float* __restrict__ y2,
    const float* __restrict__ gsum2, const float* __restrict__ gsq2,
    const float* __restrict__ g2, const float* __restrict__ be2,
    const float* __restrict__ Wm3, const float* __restrict__ bm3,
    float* __restrict__ out)
{
    __shared__ float sc[M2], sh[M2];
    const int tid = threadIdx.x;
    if (tid < M2) {
        const float mu  = gsum2[tid] * (1.f / B_EVENTS);
        const float var = gsq2[tid] * (1.f / B_EVENTS) - mu * mu;
        const float s0  = rsqrtf(var + BN_EPS) * g2[tid];
        sc[tid] = s0;
        sh[tid] = be2[tid] - mu * s0;
    }
    __syncthreads();
    const int w = tid >> 6, l = tid & 63;
    const int r = blockIdx.x * 4 + w;
    const float e0 = fmaxf(y2[(size_t)r * M2 + l]      * sc[l]      + sh[l],      0.f);
    const float e1 = fmaxf(y2[(size_t)r * M2 + 64 + l] * sc[64 + l] + sh[64 + l], 0.f);
    float a = e0 * Wm3[l] + e1 * Wm3[64 + l];
    #pragma unroll
    for (int off = 32; off >= 1; off >>= 1) a += __shfl_down(a, off, 64);
    if (l == 0) out[r] = 1.f / (1.f + expf(-(a + bm3[0])));
}

// ---------------------------------------------------------------------------
extern "C" void kernel_launch(void* const* d_in, const int* in_sizes, int n_in,
                              void* d_out, int out_size, void* d_ws, size_t ws_size,
                              hipStream_t stream) {
    const float* xa  = (const float*)d_in[0];
    const float* xb  = (const float*)d_in[1];
    const int*   si  = (const int*)  d_in[2];
    const float* W1  = (const float*)d_in[3];
    const float* b1  = (const float*)d_in[4];
    const float* W2  = (const float*)d_in[5];
    const float* b2  = (const float*)d_in[6];
    const float* W3  = (const float*)d_in[7];
    const float* b3  = (const float*)d_in[8];
    const float* Wm1 = (const float*)d_in[9];
    const float* bm1 = (const float*)d_in[10];
    const float* g1  = (const float*)d_in[11];
    const float* be1 = (const float*)d_in[12];
    const float* Wm2 = (const float*)d_in[13];
    const float* bm2 = (const float*)d_in[14];
    const float* g2  = (const float*)d_in[15];
    const float* be2 = (const float*)d_in[16];
    const float* Wm3 = (const float*)d_in[17];
    const float* bm3 = (const float*)d_in[18];
    float* out = (float*)d_out;

    char* ws = (char*)d_ws;
    size_t off = 0;
    auto alloc = [&](size_t bytes) -> void* {
        void* p = ws + off;
        off = (off + bytes + 255) & ~(size_t)255;
        return p;
    };
    float* zsum    = (float*)alloc((size_t)B_EVENTS * C3 * sizeof(float));  // 1 MB
    float* stats   = (float*)alloc(768 * sizeof(float));                    // contiguous after zsum
    int*   bounds  = (int*)  alloc((B_EVENTS + 1) * sizeof(int));
    int*   tilemap = (int*)  alloc(NTILES * sizeof(int));
    float* y1      = (float*)alloc((size_t)B_EVENTS * M1 * sizeof(float));
    float* y2      = (float*)alloc((size_t)B_EVENTS * M2 * sizeof(float));
    float* gsum1 = stats;
    float* gsq1  = stats + 256;
    float* gsum2 = stats + 512;
    float* gsq2  = stats + 640;

    // zero zsum + stats (adjacent, 256-aligned allocs)
    hipMemsetAsync(zsum, 0, (size_t)B_EVENTS * C3 * sizeof(float) + 768 * sizeof(float), stream);

    hipLaunchKernelGGL(scan_kernel, dim3(1), dim3(1024), 0, stream, si, bounds, tilemap);
    hipLaunchKernelGGL(phi_mfma_kernel, dim3(NTILES), dim3(256), 0, stream,
                       xa, bounds, tilemap, W1, W2, W3, b1, b2, b3, zsum);
    hipLaunchKernelGGL(mlp1_kernel, dim3(B_EVENTS / 8), dim3(256), 0, stream,
                       zsum, si, xb, Wm1, bm1, y1, gsum1, gsq1);
    hipLaunchKernelGGL(mlp2_kernel, dim3(B_EVENTS / 8), dim3(256), 0, stream,
                       y1, gsum1, gsq1, g1, be1, Wm2, bm2, y2, gsum2, gsq2);
    hipLaunchKernelGGL(final_kernel, dim3(B_EVENTS / 4), dim3(256), 0, stream,
                       y2, gsum2, gsq2, g2, be2, Wm3, bm3, out);
}

// Round 10
// 137.593 us; speedup vs baseline: 1.3483x; 1.3483x over previous
//
#include <hip/hip_runtime.h>
#include <hip/hip_bf16.h>

#define B_EVENTS 4096
#define L_PTS    524288
#define CIN      16
#define C1       128
#define C2       128
#define C3       64
#define DVEC     32
#define ZDIM     96   // C3 + DVEC
#define M1       256
#define M2       128
#define BN_EPS   1e-5f
#define TILE     64
#define NTILES   (L_PTS / TILE)   // 8192
#define GRID_PHI 2048
#define NTPB     (NTILES / GRID_PHI)  // 4 tiles per block

// phi LDS map (bytes)
#define XOFF     0                // X: 64pt x 4 slots x 16B = 4KB (slots 2,3 = K-pad zeros)
#define H1OFF    4096             // 16KB swizzled
#define H2OFF    20480            // 16KB swizzled
#define LDSSZ    36864

typedef __attribute__((ext_vector_type(8))) short bf16x8;
typedef __attribute__((ext_vector_type(4))) float f32x4;

// HW packed f32->bf16 (RNE), 2 values per instruction. No builtin on gfx950.
__device__ __forceinline__ unsigned cvtpk(float lo, float hi) {
    unsigned r;
    asm("v_cvt_pk_bf16_f32 %0, %1, %2" : "=v"(r) : "v"(lo), "v"(hi));
    return r;
}

// (x + b) -> relu -> pack 4 bf16 (8B)
__device__ __forceinline__ unsigned long long pack4relub(f32x4 a, f32x4 b) {
    union { unsigned u[2]; unsigned long long ll; } pk;
    pk.u[0] = cvtpk(fmaxf(a[0] + b[0], 0.f), fmaxf(a[1] + b[1], 0.f));
    pk.u[1] = cvtpk(fmaxf(a[2] + b[2], 0.f), fmaxf(a[3] + b[3], 0.f));
    return pk.ll;
}

// build a bf16x8 A-fragment from 8 consecutive f32 weights
__device__ __forceinline__ bf16x8 frag_from_f32(const float* p) {
    const float4 lo = *(const float4*)p;
    const float4 hi = *(const float4*)(p + 4);
    union { unsigned u[4]; bf16x8 v; } r;
    r.u[0] = cvtpk(lo.x, lo.y);
    r.u[1] = cvtpk(lo.z, lo.w);
    r.u[2] = cvtpk(hi.x, hi.y);
    r.u[3] = cvtpk(hi.z, hi.w);
    return r.v;
}

// H1/H2 LDS addressing: point-major, 16B slots, XOR-swizzled by pt&7
__device__ __forceinline__ int ldsoff(int base, int rowSlots, int c, int sir) {
    int s = c * rowSlots + sir;
    s ^= (c & 7);
    return base + s * 16;
}

// X LDS addressing: row pt = 4 slots of 8 channels, full XOR swizzle ->
// L1 B-frag reads (16 lanes, same g) hit 8 distinct bank-quads = conflict-free.
__device__ __forceinline__ int xaddr(int pt, int g) {
    return XOFF + (((pt * 4 + g) ^ (pt & 7)) * 16);
}

// ---------------------------------------------------------------------------
// Kernel 0: exclusive scan of counts -> bounds[B+1]; then per-tile map:
// tilemap[t] = event_of(t*64) | (fast<<30), fast = tile entirely in one event;
// -1 if tile start beyond total points. One block, 1024 threads.
// ---------------------------------------------------------------------------
__global__ __launch_bounds__(1024) void scan_kernel(const int* __restrict__ si,
                                                    int* __restrict__ bounds,
                                                    int* __restrict__ tilemap)
{
    __shared__ int sh[1024];
    const int tid = threadIdx.x;
    const int c0 = si[tid*4+0], c1 = si[tid*4+1], c2 = si[tid*4+2], c3 = si[tid*4+3];
    const int s4 = c0 + c1 + c2 + c3;
    sh[tid] = s4;
    __syncthreads();
    for (int off = 1; off < 1024; off <<= 1) {
        int add = (tid >= off) ? sh[tid - off] : 0;
        __syncthreads();
        sh[tid] += add;
        __syncthreads();
    }
    const int excl = (tid == 0) ? 0 : sh[tid - 1];
    bounds[tid*4+0] = excl;
    bounds[tid*4+1] = excl + c0;
    bounds[tid*4+2] = excl + c0 + c1;
    bounds[tid*4+3] = excl + c0 + c1 + c2;
    if (tid == 1023) bounds[B_EVENTS] = excl + s4;
    __syncthreads();

    const int total = bounds[B_EVENTS];
    for (int t = tid; t < NTILES; t += 1024) {
        const int p0 = t * TILE;
        if (p0 >= total) { tilemap[t] = -1; continue; }
        int e = (int)(((long long)p0 * B_EVENTS) / total);   // interpolation guess
        if (e > B_EVENTS - 1) e = B_EVENTS - 1;
        while (bounds[e] > p0) --e;
        while (bounds[e + 1] <= p0) ++e;
        const bool fast = (p0 + TILE <= bounds[e + 1]);
        tilemap[t] = e | (fast ? (1 << 30) : 0);
    }
}

// ---------------------------------------------------------------------------
// Kernel 1: flat phi — NTPB 64-point tiles per block (grid-stride), weights
// built once per block (round-9 lesson: one-shot blocks paid ~400cy setup per
// 64 points and regressed).  256 threads = 4 waves, M split 4-way (weights =
// 56 VGPR/wave).  Round (2 barriers): {prefetch next-X -> regs} L1 |bar1|
// L2 + write next-X |bar2| L3 + segment reduce/atomics.
// LDS: X 4KB (XOR-swizzled slots; slots 2,3 zeroed once = K-pad), H1/H2 16KB.
// 37KB -> 4 blocks/CU, VGPR ~<=128 -> ~4 waves/SIMD.
// ---------------------------------------------------------------------------
__global__ __launch_bounds__(256, 3) void phi_mfma_kernel(
    const float* __restrict__ xa,
    const int* __restrict__ bounds, const int* __restrict__ tilemap,
    const float* __restrict__ W1, const float* __restrict__ W2, const float* __restrict__ W3,
    const float* __restrict__ b1, const float* __restrict__ b2, const float* __restrict__ b3,
    float* __restrict__ zsum)
{
    __shared__ __align__(16) char lds[LDSSZ];

    const int tid  = threadIdx.x;
    const int lane = tid & 63;
    const int wm   = tid >> 6;       // wave id = M quarter (0..3)
    const int g4   = lane >> 4;      // 0..3
    const int c16  = lane & 15;      // 0..15

    // ---- issue first tile's X loads immediately (hide under setup) ----
    const int pt = tid & 63;
    const int h  = tid >> 6;         // channel quad h*4..h*4+3
    int t = blockIdx.x;
    float xv[4];
    #pragma unroll
    for (int jj = 0; jj < 4; ++jj)
        xv[jj] = xa[(size_t)(h * 4 + jj) * L_PTS + t * TILE + pt];

    // ---- biases in registers ----
    f32x4 bb1[2], bb2[2], bb3;
    #pragma unroll
    for (int mf = 0; mf < 2; ++mf) {
        bb1[mf] = *(const f32x4*)&b1[wm * 32 + mf * 16 + g4 * 4];
        bb2[mf] = *(const f32x4*)&b2[wm * 32 + mf * 16 + g4 * 4];
    }
    bb3 = *(const f32x4*)&b3[wm * 16 + g4 * 4];

    // ---- weight A-fragments straight from f32 (once per block) ----
    bf16x8 a1[2], a2[2][4], a3[4];
    {
        const bf16x8 zz = {0, 0, 0, 0, 0, 0, 0, 0};
        const int r1 = wm * 32 + c16;
        #pragma unroll
        for (int mf = 0; mf < 2; ++mf)
            a1[mf] = (g4 < 2) ? frag_from_f32(&W1[(r1 + mf * 16) * CIN + g4 * 8]) : zz;
        #pragma unroll
        for (int mf = 0; mf < 2; ++mf)
            #pragma unroll
            for (int kf = 0; kf < 4; ++kf)
                a2[mf][kf] = frag_from_f32(&W2[(r1 + mf * 16) * C1 + kf * 32 + g4 * 8]);
        const int r3 = wm * 16 + c16;
        #pragma unroll
        for (int kf = 0; kf < 4; ++kf)
            a3[kf] = frag_from_f32(&W3[r3 * C2 + kf * 32 + g4 * 8]);
    }

    // ---- zero K-pad slots 2,3 once; write first X tile ----
    {
        const int zs = 2 + (h >> 1);
        *(unsigned long long*)(lds + (((pt * 4 + zs) ^ (pt & 7)) * 16) + (h & 1) * 8) = 0ull;
        union { unsigned u[2]; unsigned long long ll; } pk;
        pk.u[0] = cvtpk(xv[0], xv[1]);
        pk.u[1] = cvtpk(xv[2], xv[3]);
        *(unsigned long long*)(lds + xaddr(pt, h >> 1) + (h & 1) * 8) = pk.ll;
    }
    __syncthreads();                           // bar0: X(tile0) ready

    for (int it = 0; it < NTPB; ++it) {
        const int tm = tilemap[t];             // uniform
        if (tm < 0) break;                     // uniform branch
        const int  e0    = tm & 0x3FFFFFFF;
        const bool fastp = (tm >> 30) & 1;
        const int  p0    = t * TILE;
        const int  tn    = t + GRID_PHI;
        const bool more  = (it + 1 < NTPB);

        // ---- prefetch next tile's X (consumed after bar1) ----
        if (more) {
            #pragma unroll
            for (int jj = 0; jj < 4; ++jj)
                xv[jj] = xa[(size_t)(h * 4 + jj) * L_PTS + tn * TILE + pt];
        }

        // ---- layer 1: H1[128ch][64pt] = relu(W1 @ X + b1), K=32 ----
        {
            f32x4 acc[2][4];
            #pragma unroll
            for (int mf = 0; mf < 2; ++mf)
                #pragma unroll
                for (int nf = 0; nf < 4; ++nf)
                    acc[mf][nf] = f32x4{0.f, 0.f, 0.f, 0.f};
            bf16x8 bfr[4];
            #pragma unroll
            for (int nf = 0; nf < 4; ++nf)
                bfr[nf] = *(const bf16x8*)(lds + xaddr(nf * 16 + c16, g4));
            __builtin_amdgcn_s_setprio(1);
            #pragma unroll
            for (int nf = 0; nf < 4; ++nf)
                #pragma unroll
                for (int mf = 0; mf < 2; ++mf)
                    acc[mf][nf] = __builtin_amdgcn_mfma_f32_16x16x32_bf16(a1[mf], bfr[nf], acc[mf][nf], 0, 0, 0);
            __builtin_amdgcn_s_setprio(0);
            #pragma unroll
            for (int mf = 0; mf < 2; ++mf) {
                const int sir = wm * 4 + mf * 2 + (g4 >> 1);
                #pragma unroll
                for (int nf = 0; nf < 4; ++nf) {
                    const int c = nf * 16 + c16;
                    *(unsigned long long*)(lds + ldsoff(H1OFF, 16, c, sir) + (g4 & 1) * 8) = pack4relub(acc[mf][nf], bb1[mf]);
                }
            }
        }
        __syncthreads();                       // bar1: H1 ready; X reads done

        // ---- layer 2: H2 = relu(W2 @ H1 + b2), K=128; plus write next-X ----
        {
            f32x4 acc[2][4];
            #pragma unroll
            for (int mf = 0; mf < 2; ++mf)
                #pragma unroll
                for (int nf = 0; nf < 4; ++nf)
                    acc[mf][nf] = f32x4{0.f, 0.f, 0.f, 0.f};
            #pragma unroll
            for (int nf = 0; nf < 4; ++nf) {
                const int c = nf * 16 + c16;
                bf16x8 bk[4];
                #pragma unroll
                for (int kf = 0; kf < 4; ++kf)
                    bk[kf] = *(const bf16x8*)(lds + ldsoff(H1OFF, 16, c, kf * 4 + g4));
                __builtin_amdgcn_s_setprio(1);
                #pragma unroll
                for (int mf = 0; mf < 2; ++mf)
                    #pragma unroll
                    for (int kf = 0; kf < 4; ++kf)
                        acc[mf][nf] = __builtin_amdgcn_mfma_f32_16x16x32_bf16(a2[mf][kf], bk[kf], acc[mf][nf], 0, 0, 0);
                __builtin_amdgcn_s_setprio(0);
            }
            if (more) {   // WAR-safe: all L1 X-reads completed at bar1
                union { unsigned u[2]; unsigned long long ll; } pk;
                pk.u[0] = cvtpk(xv[0], xv[1]);
                pk.u[1] = cvtpk(xv[2], xv[3]);
                *(unsigned long long*)(lds + xaddr(pt, h >> 1) + (h & 1) * 8) = pk.ll;
            }
            #pragma unroll
            for (int mf = 0; mf < 2; ++mf) {
                const int sir = wm * 4 + mf * 2 + (g4 >> 1);
                #pragma unroll
                for (int nf = 0; nf < 4; ++nf) {
                    const int c = nf * 16 + c16;
                    *(unsigned long long*)(lds + ldsoff(H2OFF, 16, c, sir) + (g4 & 1) * 8) = pack4relub(acc[mf][nf], bb2[mf]);
                }
            }
        }
        __syncthreads();                       // bar2: H2 + next-X ready

        // ---- layer 3: H3 = relu(W3 @ H2 + b3); segment column-sum atomics ----
        {
            f32x4 acc3[4];
            #pragma unroll
            for (int nf = 0; nf < 4; ++nf) acc3[nf] = f32x4{0.f, 0.f, 0.f, 0.f};
            #pragma unroll
            for (int nf = 0; nf < 4; ++nf) {
                const int c = nf * 16 + c16;
                bf16x8 bk[4];
                #pragma unroll
                for (int kf = 0; kf < 4; ++kf)
                    bk[kf] = *(const bf16x8*)(lds + ldsoff(H2OFF, 16, c, kf * 4 + g4));
                __builtin_amdgcn_s_setprio(1);
                #pragma unroll
                for (int kf = 0; kf < 4; ++kf)
                    acc3[nf] = __builtin_amdgcn_mfma_f32_16x16x32_bf16(a3[kf], bk[kf], acc3[nf], 0, 0, 0);
                __builtin_amdgcn_s_setprio(0);
            }

            if (fastp) {
                float s[4] = {0.f, 0.f, 0.f, 0.f};
                #pragma unroll
                for (int nf = 0; nf < 4; ++nf)
                    #pragma unroll
                    for (int r = 0; r < 4; ++r)
                        s[r] += fmaxf(acc3[nf][r] + bb3[r], 0.f);
                #pragma unroll
                for (int r = 0; r < 4; ++r) {
                    float v = s[r];
                    v += __shfl_xor(v, 1, 64);
                    v += __shfl_xor(v, 2, 64);
                    v += __shfl_xor(v, 4, 64);
                    v += __shfl_xor(v, 8, 64);
                    s[r] = v;
                }
                if (c16 == 0) {
                    #pragma unroll
                    for (int r = 0; r < 4; ++r)
                        atomicAdd(&zsum[(size_t)e0 * C3 + wm * 16 + g4 * 4 + r], s[r]);
                }
            } else {
                const int total = bounds[B_EVENTS];
                #pragma unroll
                for (int nf = 0; nf < 4; ++nf) {
                    const int col = p0 + nf * 16 + c16;
                    if (col < total) {
                        int sgr = e0;
                        while (col >= bounds[sgr + 1]) ++sgr;
                        #pragma unroll
                        for (int r = 0; r < 4; ++r)
                            atomicAdd(&zsum[(size_t)sgr * C3 + wm * 16 + g4 * 4 + r],
                                      fmaxf(acc3[nf][r] + bb3[r], 0.f));
                    }
                }
            }
        }
        // no barrier: next L1 reads X (bar2-protected) and writes H1 (its last
        // reader, L2, finished pre-bar2); L3's H2 reads precede next bar1.
        t = tn;
    }
}

// ---------------------------------------------------------------------------
// Kernel 2: y1 = z @ Wm1.T + bm1, z = [zsum/cnt , xb]; plus column stats
// ---------------------------------------------------------------------------
__global__ __launch_bounds__(256) void mlp1_kernel(
    const float* __restrict__ zsum, const int* __restrict__ si, const float* __restrict__ xb,
    const float* __restrict__ Wm1, const float* __restrict__ bm1,
    float* __restrict__ y1, float* __restrict__ gsum, float* __restrict__ gsq)
{
    __shared__ float zs[8][ZDIM + 4];
    const int r0 = blockIdx.x * 8;
    const int tid = threadIdx.x;
    for (int i = tid; i < 8 * ZDIM; i += 256) {
        const int r = i / ZDIM, c = i - r * ZDIM;
        float v;
        if (c < C3) {
            const int cnt = si[r0 + r];
            v = zsum[(size_t)(r0 + r) * C3 + c] / (float)max(cnt, 1);
        } else {
            v = xb[(size_t)(r0 + r) * DVEC + (c - C3)];
        }
        zs[r][c] = v;
    }
    __syncthreads();
    const int o = tid;
    float acc[8];
    const float bb = bm1[o];
    #pragma unroll
    for (int r = 0; r < 8; ++r) acc[r] = bb;
    for (int c = 0; c < ZDIM; c += 4) {
        const float4 w = *(const float4*)&Wm1[o * ZDIM + c];
        #pragma unroll
        for (int r = 0; r < 8; ++r) {
            const float4 v = *(const float4*)&zs[r][c];
            acc[r] += w.x*v.x + w.y*v.y + w.z*v.z + w.w*v.w;
        }
    }
    float s = 0.f, sq = 0.f;
    #pragma unroll
    for (int r = 0; r < 8; ++r) {
        y1[(size_t)(r0 + r) * M1 + o] = acc[r];
        s += acc[r]; sq += acc[r] * acc[r];
    }
    atomicAdd(&gsum[o], s);
    atomicAdd(&gsq[o], sq);
}

// ---------------------------------------------------------------------------
// Kernel 3: y2 = relu(bn(y1)) @ Wm2.T + bm2, BN1 finalize fused; plus stats
// ---------------------------------------------------------------------------
__global__ __launch_bounds__(256) void mlp2_kernel(
    const float* __restrict__ y1,
    const float* __restrict__ gsum1, const float* __restrict__ gsq1,
    const float* __restrict__ g1, const float* __restrict__ be1,
    const float* __restrict__ Wm2, const float* __restrict__ bm2,
    float* __restrict__ y2, float* __restrict__ gsum, float* __restrict__ gsq)
{
    __shared__ float zs[8][M1 + 4];
    __shared__ float sc[M1], sh[M1];
    const int r0 = blockIdx.x * 8;
    const int tid = threadIdx.x;
    {
        const float mu  = gsum1[tid] * (1.f / B_EVENTS);
        const float var = gsq1[tid] * (1.f / B_EVENTS) - mu * mu;
        const float s0  = rsqrtf(var + BN_EPS) * g1[tid];
        sc[tid] = s0;
        sh[tid] = be1[tid] - mu * s0;
    }
    __syncthreads();
    for (int i = tid; i < 8 * M1; i += 256) {
        const int r = i >> 8, c = i & (M1 - 1);
        const float v = y1[(size_t)(r0 + r) * M1 + c];
        zs[r][c] = fmaxf(v * sc[c] + sh[c], 0.f);
    }
    __syncthreads();
    const int o = tid & 127;
    const int h = tid >> 7;
    float acc[4];
    const float bb = bm2[o];
    #pragma unroll
    for (int r = 0; r < 4; ++r) acc[r] = bb;
    for (int c = 0; c < M1; c += 4) {
        const float4 w = *(const float4*)&Wm2[o * M1 + c];
        #pragma unroll
        for (int r = 0; r < 4; ++r) {
            const float4 v = *(const float4*)&zs[h * 4 + r][c];
            acc[r] += w.x*v.x + w.y*v.y + w.z*v.z + w.w*v.w;
        }
    }
    float s = 0.f, sq = 0.f;
    #pragma unroll
    for (int r = 0; r < 4; ++r) {
        y2[(size_t)(r0 + h * 4 + r) * M2 + o] = acc[r];
        s += acc[r]; sq += acc[r] * acc[r];
    }
    atomicAdd(&gsum[o], s);
    atomicAdd(&gsq[o], sq);
}

// ---------------------------------------------------------------------------
// Kernel 4: out = sigmoid(relu(bn(y2)) @ Wm3.T + bm3), BN2 finalize fused
// ---------------------------------------------------------------------------
__global__ __launch_bounds__(256) void final_kernel(
    const float* __restrict__ y2,
    const float* __restrict__ gsum2, const float* __restrict__ gsq2,
    const float* __restrict__ g2, const float* __restrict__ be2,
    const float* __restrict__ Wm3, const float* __restrict__ bm3,
    float* __restrict__ out)
{
    __shared__ float sc[M2], sh[M2];
    const int tid = threadIdx.x;
    if (tid < M2) {
        const float mu  = gsum2[tid] * (1.f / B_EVENTS);
        const float var = gsq2[tid] * (1.f / B_EVENTS) - mu * mu;
        const float s0  = rsqrtf(var + BN_EPS) * g2[tid];
        sc[tid] = s0;
        sh[tid] = be2[tid] - mu * s0;
    }
    __syncthreads();
    const int w = tid >> 6, l = tid & 63;
    const int r = blockIdx.x * 4 + w;
    const float e0 = fmaxf(y2[(size_t)r * M2 + l]      * sc[l]      + sh[l],      0.f);
    const float e1 = fmaxf(y2[(size_t)r * M2 + 64 + l] * sc[64 + l] + sh[64 + l], 0.f);
    float a = e0 * Wm3[l] + e1 * Wm3[64 + l];
    #pragma unroll
    for (int off = 32; off >= 1; off >>= 1) a += __shfl_down(a, off, 64);
    if (l == 0) out[r] = 1.f / (1.f + expf(-(a + bm3[0])));
}

// ---------------------------------------------------------------------------
extern "C" void kernel_launch(void* const* d_in, const int* in_sizes, int n_in,
                              void* d_out, int out_size, void* d_ws, size_t ws_size,
                              hipStream_t stream) {
    const float* xa  = (const float*)d_in[0];
    const float* xb  = (const float*)d_in[1];
    const int*   si  = (const int*)  d_in[2];
    const float* W1  = (const float*)d_in[3];
    const float* b1  = (const float*)d_in[4];
    const float* W2  = (const float*)d_in[5];
    const float* b2  = (const float*)d_in[6];
    const float* W3  = (const float*)d_in[7];
    const float* b3  = (const float*)d_in[8];
    const float* Wm1 = (const float*)d_in[9];
    const float* bm1 = (const float*)d_in[10];
    const float* g1  = (const float*)d_in[11];
    const float* be1 = (const float*)d_in[12];
    const float* Wm2 = (const float*)d_in[13];
    const float* bm2 = (const float*)d_in[14];
    const float* g2  = (const float*)d_in[15];
    const float* be2 = (const float*)d_in[16];
    const float* Wm3 = (const float*)d_in[17];
    const float* bm3 = (const float*)d_in[18];
    float* out = (float*)d_out;

    char* ws = (char*)d_ws;
    size_t off = 0;
    auto alloc = [&](size_t bytes) -> void* {
        void* p = ws + off;
        off = (off + bytes + 255) & ~(size_t)255;
        return p;
    };
    float* zsum    = (float*)alloc((size_t)B_EVENTS * C3 * sizeof(float));  // 1 MB
    float* stats   = (float*)alloc(768 * sizeof(float));                    // contiguous after zsum
    int*   bounds  = (int*)  alloc((B_EVENTS + 1) * sizeof(int));
    int*   tilemap = (int*)  alloc(NTILES * sizeof(int));
    float* y1      = (float*)alloc((size_t)B_EVENTS * M1 * sizeof(float));
    float* y2      = (float*)alloc((size_t)B_EVENTS * M2 * sizeof(float));
    float* gsum1 = stats;
    float* gsq1  = stats + 256;
    float* gsum2 = stats + 512;
    float* gsq2  = stats + 640;

    // zero zsum + stats (adjacent, 256-aligned allocs)
    hipMemsetAsync(zsum, 0, (size_t)B_EVENTS * C3 * sizeof(float) + 768 * sizeof(float), stream);

    hipLaunchKernelGGL(scan_kernel, dim3(1), dim3(1024), 0, stream, si, bounds, tilemap);
    hipLaunchKernelGGL(phi_mfma_kernel, dim3(GRID_PHI), dim3(256), 0, stream,
                       xa, bounds, tilemap, W1, W2, W3, b1, b2, b3, zsum);
    hipLaunchKernelGGL(mlp1_kernel, dim3(B_EVENTS / 8), dim3(256), 0, stream,
                       zsum, si, xb, Wm1, bm1, y1, gsum1, gsq1);
    hipLaunchKernelGGL(mlp2_kernel, dim3(B_EVENTS / 8), dim3(256), 0, stream,
                       y1, gsum1, gsq1, g1, be1, Wm2, bm2, y2, gsum2, gsq2);
    hipLaunchKernelGGL(final_kernel, dim3(B_EVENTS / 4), dim3(256), 0, stream,
                       y2, gsum2, gsq2, g2, be2, Wm3, bm3, out);
}